// Round 2
// baseline (251.737 us; speedup 1.0000x reference)
//
#include <hip/hip_runtime.h>

#define BATCH   1024
#define IN      1024
#define OUT     40960
#define KF      7
#define OSTRIP  32                 // outputs per wave
#define THREADS 256                // 4 waves/block
#define LDS_STRIDE 36              // dwords per b-row: 32 o + 4 pad -> rows 16B-aligned, conflict-free

// ---------- pre-kernel: xT[i][b] = x[b][i]  (4 MB, lives in d_ws, L2-resident) ----------
__global__ __launch_bounds__(256)
void transpose_x(const float* __restrict__ x, float* __restrict__ xT)
{
    __shared__ float tile[64][65];
    const int t  = threadIdx.x;
    const int c  = t & 63;
    const int r0 = t >> 6;                  // 0..3
    const int bx = blockIdx.x * 64;         // col base in x
    const int by = blockIdx.y * 64;         // row base in x
#pragma unroll
    for (int rr = 0; rr < 16; ++rr) {
        int r = r0 + rr * 4;
        tile[r][c] = x[(size_t)(by + r) * IN + bx + c];
    }
    __syncthreads();
#pragma unroll
    for (int rr = 0; rr < 16; ++rr) {
        int r = r0 + rr * 4;
        xT[(size_t)(bx + r) * BATCH + by + c] = tile[c][r];
    }
}

// ---------- main kernel: wave-uniform idx -> coalesced L2 gathers ----------
// lane = batch row; wave processes OSTRIP outputs; idx/vals are wave-uniform
// (forced to SGPR via readfirstlane) so each x access is
//   global_load_dword v, v_lane4, s[xT + idx*1024 + btile]   -- 256 B coalesced.
__global__ __launch_bounds__(THREADS, 4)
void sparse_proj_t(const float* __restrict__ xT, const float* __restrict__ vals,
                   const int* __restrict__ idx, float* __restrict__ y)
{
    __shared__ float tile[4 * 64 * LDS_STRIDE];   // 36 KB -> 4 blocks/CU

    const int lane  = threadIdx.x & 63;
    const int w     = __builtin_amdgcn_readfirstlane(threadIdx.x >> 6);
    const int btile = blockIdx.y * 64;
    const int obase = blockIdx.x * (4 * OSTRIP) + w * OSTRIP;

    const float* xTb   = xT + btile;              // uniform
    float*       wtile = &tile[w * 64 * LDS_STRIDE];

    float4 acc4[OSTRIP / 4];

#pragma unroll 2
    for (int g = 0; g < OSTRIP / 4; ++g) {
        float comp[4];
#pragma unroll
        for (int c = 0; c < 4; ++c) {
            const int o = obase + g * 4 + c;                  // wave-uniform
            const int*   ip = idx  + (size_t)o * KF;
            const float* vp = vals + (size_t)o * KF;
            float a = 0.0f;
#pragma unroll
            for (int k = 0; k < KF; ++k) {
                const int   si = __builtin_amdgcn_readfirstlane(ip[k]); // force SGPR
                const float v  = vp[k];                                  // uniform -> s_load
                a = fmaf(v, xTb[(size_t)si * BATCH + lane], a);          // coalesced gather
            }
            comp[c] = a;
        }
        acc4[g] = make_float4(comp[0], comp[1], comp[2], comp[3]);
    }

    // per-lane row in LDS: wtile[lane*36 + oo] = y[btile+lane][obase+oo]
    {
        float4* myrow = (float4*)&wtile[lane * LDS_STRIDE];   // 144 B row stride: 16B-aligned
#pragma unroll
        for (int g = 0; g < OSTRIP / 4; ++g) myrow[g] = acc4[g];
    }
    __syncthreads();   // cheap; guarantees LDS visibility before transposed read

    // store: lane -> (br = 2s + lane/32, oc = lane%32); two 128 B segments/instr
#pragma unroll 4
    for (int s = 0; s < 32; ++s) {
        const int br = 2 * s + (lane >> 5);
        const int oc = lane & 31;
        const float val = wtile[br * LDS_STRIDE + oc];
        __builtin_nontemporal_store(val, &y[(size_t)(btile + br) * OUT + obase + oc]);
    }
}

extern "C" void kernel_launch(void* const* d_in, const int* in_sizes, int n_in,
                              void* d_out, int out_size, void* d_ws, size_t ws_size,
                              hipStream_t stream) {
    const float* x    = (const float*)d_in[0];   // [1024, 1024] fp32
    const float* vals = (const float*)d_in[1];   // [40960, 7]  fp32
    const int*   idx  = (const int*)d_in[2];     // [40960, 7]  int32
    float*       y    = (float*)d_out;           // [1024, 40960] fp32
    float*       xT   = (float*)d_ws;            // 4 MB scratch

    transpose_x<<<dim3(IN / 64, BATCH / 64), dim3(256), 0, stream>>>(x, xT);

    dim3 grid(OUT / (4 * OSTRIP), BATCH / 64);   // (320, 16) = 5120 blocks
    sparse_proj_t<<<grid, dim3(THREADS), 0, stream>>>(xT, vals, idx, y);
}

// Round 4
// 207.506 us; speedup vs baseline: 1.2132x; 1.2132x over previous
//
#include <hip/hip_runtime.h>

#define BATCH   1024
#define IN      1024
#define OUT     40960
#define KF      7
#define OSTRIP  32                 // outputs per wave
#define THREADS 256                // 4 waves/block -> 128 outputs/block
#define OBLOCK  (4 * OSTRIP)       // 128
#define TSTRIDE (OBLOCK + 4)       // 132 dwords/row: 16B-aligned rows, padded

typedef float floatx4 __attribute__((ext_vector_type(4)));  // clang-native: OK for nontemporal builtins

// ---------- pre-kernel: xT[i][b] = x[b][i]  (4 MB, lives in d_ws, L2-resident) ----------
__global__ __launch_bounds__(256)
void transpose_x(const float* __restrict__ x, float* __restrict__ xT)
{
    __shared__ float tile[64][65];
    const int t  = threadIdx.x;
    const int c  = t & 63;
    const int r0 = t >> 6;                  // 0..3
    const int bx = blockIdx.x * 64;         // col base in x
    const int by = blockIdx.y * 64;         // row base in x
#pragma unroll
    for (int rr = 0; rr < 16; ++rr) {
        int r = r0 + rr * 4;
        tile[r][c] = x[(size_t)(by + r) * IN + bx + c];
    }
    __syncthreads();
#pragma unroll
    for (int rr = 0; rr < 16; ++rr) {
        int r = r0 + rr * 4;
        xT[(size_t)(bx + r) * BATCH + by + c] = tile[c][r];
    }
}

// ---------- main kernel ----------
// Gather phase (verified in R2): lane = batch row, idx/vals are wave-uniform
// -> SGPR, each x access is a 256 B coalesced load from the L2-resident xT.
// Store phase: block-cooperative. All 4 waves write their 32-o strips into
// one 64-row x 128-o LDS tile; then 256 threads store float4 so every
// wave-instruction writes rows as full 512 B contiguous aligned runs --
// eliminates the 128 B partial-segment NT writes that doubled WRITE_SIZE in R2.
__global__ __launch_bounds__(THREADS, 4)
void sparse_proj_t(const float* __restrict__ xT, const float* __restrict__ vals,
                   const int* __restrict__ idx, float* __restrict__ y)
{
    __shared__ float tile[64 * TSTRIDE];          // 33 KB -> 4 blocks/CU

    const int t      = threadIdx.x;
    const int lane   = t & 63;
    const int w      = __builtin_amdgcn_readfirstlane(t >> 6);
    const int btile  = blockIdx.y * 64;
    const int oblock = blockIdx.x * OBLOCK;
    const int obase  = oblock + w * OSTRIP;

    const float* xTb = xT + btile;                // uniform

    floatx4 acc4[OSTRIP / 4];

#pragma unroll 2
    for (int g = 0; g < OSTRIP / 4; ++g) {
        float comp[4];
#pragma unroll
        for (int c = 0; c < 4; ++c) {
            const int o = obase + g * 4 + c;                  // wave-uniform
            const int*   ip = idx  + (size_t)o * KF;
            const float* vp = vals + (size_t)o * KF;
            float a = 0.0f;
#pragma unroll
            for (int k = 0; k < KF; ++k) {
                const int   si = __builtin_amdgcn_readfirstlane(ip[k]); // SGPR
                const float v  = vp[k];                                  // uniform
                a = fmaf(v, xTb[(size_t)si * BATCH + lane], a);          // 256 B coalesced
            }
            comp[c] = a;
        }
        acc4[g] = (floatx4){comp[0], comp[1], comp[2], comp[3]};
    }

    // ---- deposit accumulators: tile[b_row * TSTRIDE + o_off] ----
#pragma unroll
    for (int g = 0; g < OSTRIP / 4; ++g) {
        *(floatx4*)&tile[lane * TSTRIDE + w * OSTRIP + g * 4] = acc4[g];
    }
    __syncthreads();

    // ---- block-wide store: thread t -> row r = t>>5 (+8/iter), col c4 = t&31
    // each wave-instruction: 2 rows x 32 lanes x 16 B = 512 B contiguous/row ----
    {
        const int c4 = t & 31;
        const int r0 = t >> 5;                    // 0..7
#pragma unroll
        for (int it = 0; it < 8; ++it) {
            const int r = r0 + it * 8;
            const floatx4 v4 = *(const floatx4*)&tile[r * TSTRIDE + c4 * 4];
            __builtin_nontemporal_store(
                v4, (floatx4*)&y[(size_t)(btile + r) * OUT + oblock + c4 * 4]);
        }
    }
}

extern "C" void kernel_launch(void* const* d_in, const int* in_sizes, int n_in,
                              void* d_out, int out_size, void* d_ws, size_t ws_size,
                              hipStream_t stream) {
    const float* x    = (const float*)d_in[0];   // [1024, 1024] fp32
    const float* vals = (const float*)d_in[1];   // [40960, 7]  fp32
    const int*   idx  = (const int*)d_in[2];     // [40960, 7]  int32
    float*       y    = (float*)d_out;           // [1024, 40960] fp32
    float*       xT   = (float*)d_ws;            // 4 MB scratch

    transpose_x<<<dim3(IN / 64, BATCH / 64), dim3(256), 0, stream>>>(x, xT);

    dim3 grid(OUT / OBLOCK, BATCH / 64);         // (320, 16) = 5120 blocks
    sparse_proj_t<<<grid, dim3(THREADS), 0, stream>>>(xT, vals, idx, y);
}